// Round 1
// baseline (519.004 us; speedup 1.0000x reference)
//
#include <hip/hip_runtime.h>
#include <hip/hip_bf16.h>

// Spatial RNN, 4 directions, R=8, C=64.
// One block per (direction, line). Line = row (left/right) or column (up/down).
// Reversed directions (right/down) are handled by negative pixel strides so the
// local recurrence is always t[p] = relu(t[p-1] @ W), t[-1] = 0.
//
// MFMA mapping (16x16x32 bf16): D[d][p] = sum_c W[c][d] * t[p-1][c]
//   A-operand = W^T fragments (loaded once to regs), M = out-channel
//   B-operand = t fragments from LDS,                 N = pixel
// D-fragment regs = 4 consecutive out-channels of one pixel -> ds_write_b64.

#define HD 192
#define CH 64
#define RSTEPS 8
#define TSTRIDE 72   // shorts per pixel row in t buffers (64 + 8 pad -> 144B = 36 banks)
#define SLOTS 193    // pixel slots incl. zero slot at index 0 (= t[-1])
#define STG_STRIDE 68 // floats per pixel row in fp32 staging (272B, 16B-aligned)

typedef __attribute__((ext_vector_type(8))) short short8v;
typedef __attribute__((ext_vector_type(4))) float float4v;

static __device__ __forceinline__ short f2bf_rne(float f) {
    unsigned u = __float_as_uint(f);
    u += 0x7FFFu + ((u >> 16) & 1u);
    return (short)(u >> 16);
}

__global__ __launch_bounds__(256) void spatial_rnn_kernel(
    const float* __restrict__ x,
    const float* __restrict__ Wl,
    const float* __restrict__ Wr,
    const float* __restrict__ Wu,
    const float* __restrict__ Wd,
    float* __restrict__ out)
{
    __shared__ __align__(16) short smem_s[2 * SLOTS * TSTRIDE];
    short* tb0 = smem_s;
    short* tb1 = smem_s + SLOTS * TSTRIDE;
    float* stg = (float*)smem_s;   // reused after the step loop (52,224B <= 55,584B)

    const int tid  = threadIdx.x;
    const int dir  = blockIdx.y;
    const int line = blockIdx.x;
    const int b    = line / HD;
    const int rc   = line - b * HD;

    const float* Wp = (dir == 0) ? Wl : (dir == 1) ? Wr : (dir == 2) ? Wu : Wd;

    int xbase, xstride, obase, ostride;
    if (dir == 0) {        // left: out[w] uses in[w-1]; forward along w
        xbase   = (b * HD + rc) * HD * CH;
        xstride = CH;
        obase   = (b * HD + rc) * HD * 256;
        ostride = 256;
    } else if (dir == 1) { // right: out[w] uses in[w+1]; reversed along w
        xbase   = ((b * HD + rc) * HD + (HD - 1)) * CH;
        xstride = -CH;
        obase   = ((b * HD + rc) * HD + (HD - 1)) * 256 + 64;
        ostride = -256;
    } else if (dir == 2) { // up: out[h] uses in[h-1]; forward along h
        xbase   = b * HD * HD * CH + rc * CH;
        xstride = HD * CH;
        obase   = b * HD * HD * 256 + rc * 256 + 128;
        ostride = HD * 256;
    } else {               // down: out[h] uses in[h+1]; reversed along h
        xbase   = ((b * HD + (HD - 1)) * HD + rc) * CH;
        xstride = -HD * CH;
        obase   = ((b * HD + (HD - 1)) * HD + rc) * 256 + 192;
        ostride = -HD * 256;
    }

    // ---- load x line -> t buffer 0 (bf16), zero slot 0 of both buffers ----
    for (int q = tid; q < HD * 16; q += 256) {
        int p  = q >> 4;
        int c4 = (q & 15) << 2;
        const float4 v = *(const float4*)(x + xbase + p * xstride + c4);
        short4 s;
        s.x = f2bf_rne(v.x); s.y = f2bf_rne(v.y);
        s.z = f2bf_rne(v.z); s.w = f2bf_rne(v.w);
        *(short4*)(tb0 + (p + 1) * TSTRIDE + c4) = s;
    }
    if (tid < TSTRIDE) { tb0[tid] = 0; tb1[tid] = 0; }

    // ---- W fragments (A operand): A[d][c] = W[c][d] ----
    const int lane = tid & 63;
    const int wv   = tid >> 6;
    const int q4   = lane >> 4;
    const int l16  = lane & 15;

    short8v Af[2][4];
    #pragma unroll
    for (int kc = 0; kc < 2; ++kc)
        #pragma unroll
        for (int dt = 0; dt < 4; ++dt)
            #pragma unroll
            for (int j = 0; j < 8; ++j)
                Af[kc][dt][j] = f2bf_rne(Wp[(kc * 32 + q4 * 8 + j) * CH + dt * 16 + l16]);

    float4v acc[3][4];
    #pragma unroll
    for (int i = 0; i < 3; ++i)
        #pragma unroll
        for (int dt = 0; dt < 4; ++dt)
            acc[i][dt] = (float4v){0.f, 0.f, 0.f, 0.f};

    __syncthreads();

    // ---- 8 recurrent steps, ping-pong LDS buffers ----
    for (int k = 0; k < RSTEPS; ++k) {
        const short* cur = (k & 1) ? tb1 : tb0;
        short*       nxt = (k & 1) ? tb0 : tb1;
        #pragma unroll
        for (int i = 0; i < 3; ++i) {
            const int pb   = (wv + i * 4) * 16;   // pixel-tile base
            const int slot = pb + l16;            // slot p holds t_prev[p-1]
            short8v B0 = *(const short8v*)(cur + slot * TSTRIDE + q4 * 8);
            short8v B1 = *(const short8v*)(cur + slot * TSTRIDE + 32 + q4 * 8);
            #pragma unroll
            for (int dt = 0; dt < 4; ++dt) {
                float4v d = {0.f, 0.f, 0.f, 0.f};
                d = __builtin_amdgcn_mfma_f32_16x16x32_bf16(Af[0][dt], B0, d, 0, 0, 0);
                d = __builtin_amdgcn_mfma_f32_16x16x32_bf16(Af[1][dt], B1, d, 0, 0, 0);
                float v0 = fmaxf(d[0], 0.f);
                float v1 = fmaxf(d[1], 0.f);
                float v2 = fmaxf(d[2], 0.f);
                float v3 = fmaxf(d[3], 0.f);
                acc[i][dt][0] += v0; acc[i][dt][1] += v1;
                acc[i][dt][2] += v2; acc[i][dt][3] += v3;
                if (k < RSTEPS - 1) {
                    __hip_bfloat162 h01 = __float22bfloat162_rn(make_float2(v0, v1));
                    __hip_bfloat162 h23 = __float22bfloat162_rn(make_float2(v2, v3));
                    uint2 wpk;
                    __builtin_memcpy(&wpk.x, &h01, 4);
                    __builtin_memcpy(&wpk.y, &h23, 4);
                    // t_new[pixel = pb+l16][channel = dt*16 + q4*4 + r], r=0..3
                    *(uint2*)(nxt + (pb + l16 + 1) * TSTRIDE + dt * 16 + q4 * 4) = wpk;
                }
            }
        }
        __syncthreads();
    }

    // ---- stage fp32 accumulator to LDS for coalesced output ----
    #pragma unroll
    for (int i = 0; i < 3; ++i) {
        const int pb = (wv + i * 4) * 16;
        #pragma unroll
        for (int dt = 0; dt < 4; ++dt) {
            *(float4v*)(stg + (pb + l16) * STG_STRIDE + dt * 16 + q4 * 4) = acc[i][dt];
        }
    }
    __syncthreads();

    // ---- out = x + sum(t_k), coalesced float4 writes ----
    for (int q = tid; q < HD * 16; q += 256) {
        int p  = q >> 4;
        int c4 = (q & 15) << 2;
        const float4  xv = *(const float4*)(x + xbase + p * xstride + c4);
        const float4v sv = *(const float4v*)(stg + p * STG_STRIDE + c4);
        float4 o;
        o.x = xv.x + sv[0]; o.y = xv.y + sv[1];
        o.z = xv.z + sv[2]; o.w = xv.w + sv[3];
        *(float4*)(out + obase + p * ostride + c4) = o;
    }
}

extern "C" void kernel_launch(void* const* d_in, const int* in_sizes, int n_in,
                              void* d_out, int out_size, void* d_ws, size_t ws_size,
                              hipStream_t stream) {
    const float* x  = (const float*)d_in[0];
    const float* Wl = (const float*)d_in[1];
    const float* Wr = (const float*)d_in[2];
    const float* Wu = (const float*)d_in[3];
    const float* Wd = (const float*)d_in[4];
    float* outp = (float*)d_out;
    dim3 grid(8 * HD, 4);
    spatial_rnn_kernel<<<grid, 256, 0, stream>>>(x, Wl, Wr, Wu, Wd, outp);
}